// Round 15
// baseline (256.142 us; speedup 1.0000x reference)
//
#include <hip/hip_runtime.h>
#include <math.h>

// (S,N,B,T,D) = (8,8,2,2048,1024)
// R7 structure (best: 92.7us) cleaned:
//  - grid 8192 = (xcd 8) x (k 1024); XCD owns contiguous btp range; k%4 = s-pair
//  - block 256 thr = 4 waves; waves {0,1} -> bt_a, {2,3} -> bt_b; 2 chunks/thread
//  - V register-resident through phase E (FETCH=131MB proven)
//  - static lane63 exchange (no dynamic reg indexing)
//  - scalar combine via uniform LDS float4 broadcasts (no 28x readlane chain)
//  - nontemporal merged_out stores via native vector type (don't evict V/P)
//  - natural VGPR (no launch_bounds: R8/R9/R10 allocator lessons)
#define TPB 256

typedef float vf4 __attribute__((ext_vector_type(4)));   // native vector for nt-store

template <int CTRL>
__device__ __forceinline__ float dpp_add(float x) {
    int yi = __builtin_amdgcn_update_dpp(0, __float_as_int(x), CTRL, 0xF, 0xF, true);
    return x + __int_as_float(yi);
}

// 64-lane sum, pure VALU; TOTAL lands in lane 63.
__device__ __forceinline__ float wave_sum63(float x) {
    x = dpp_add<0xB1>(x);    // xor 1
    x = dpp_add<0x4E>(x);    // xor 2
    x = dpp_add<0x141>(x);   // row_half_mirror
    x = dpp_add<0x140>(x);   // row_mirror -> 16-lane row sums
    x = dpp_add<0x142>(x);   // row_bcast15
    x = dpp_add<0x143>(x);   // row_bcast31 -> lane63 = total
    return x;
}

__device__ __forceinline__ float dot4(const float4 a, const float4 b) {
    return a.x*b.x + a.y*b.y + a.z*b.z + a.w*b.w;
}

__device__ __forceinline__ void nt_store4(float* p, float x, float y, float z, float w) {
    vf4 t; t.x = x; t.y = y; t.z = z; t.w = w;
    __builtin_nontemporal_store(t, (vf4*)p);
}

__global__ void two_phase_attn_kernel(
    const float* __restrict__ q,    // [8][1024]
    const float* __restrict__ V,    // block_reps  [8][2][2048][1024]
    const float* __restrict__ P,    // partial_sums[8][2][2048][1024]
    const float* __restrict__ wgt,  // [1024]
    float* __restrict__ out)        // merged_out | merged_max | merged_lse
{
    constexpr int    N   = 8;
    constexpr int    BT  = 4096;
    constexpr int    D   = 1024;
    constexpr size_t ROW = (size_t)BT * D;
    constexpr size_t OUT_MM  = (size_t)8 * ROW;
    constexpr size_t OUT_LSE = OUT_MM + (size_t)BT * 8;
    constexpr float  SCALE = 0.03125f;
    constexpr float  EPS   = 1e-6f;

    __shared__ float red[4][28];    // per-wave reduced partials (448 B)

    const int tid  = threadIdx.x;
    const int w    = tid >> 6;
    const int lane = tid & 63;

    // XCD-aware decomposition (dispatch round-robins blockIdx % 8 -> XCD)
    const int b   = blockIdx.x;
    const int xcd = b & 7;
    const int k   = b >> 3;
    const int btp = xcd * 256 + (k >> 2);
    const int sp  = k & 3;
    const int s0  = 2 * sp, s1 = s0 + 1;

    const int bt  = 2 * btp + (w >> 1);          // waves 0,1 -> bt_a; 2,3 -> bt_b
    const int d0  = (w & 1) * 512 + lane * 4;    // owns d0 and d0+256
    const size_t btD = (size_t)bt * D;

    // ---- All global loads issued up front (26 independent float4/thread) ----
    float4 v[N][2];
    #pragma unroll
    for (int n = 0; n < N; ++n) {
        v[n][0] = *(const float4*)(V + (size_t)n * ROW + btD + d0);
        v[n][1] = *(const float4*)(V + (size_t)n * ROW + btD + d0 + 256);
    }
    float4 p0[2], p1[2];
    p0[0] = *(const float4*)(P + (size_t)s0 * ROW + btD + d0);
    p0[1] = *(const float4*)(P + (size_t)s0 * ROW + btD + d0 + 256);
    p1[0] = *(const float4*)(P + (size_t)s1 * ROW + btD + d0);
    p1[1] = *(const float4*)(P + (size_t)s1 * ROW + btD + d0 + 256);

    float4 qw0[2], qw1[2];
    #pragma unroll
    for (int c = 0; c < 2; ++c) {
        const int d = d0 + c * 256;
        const float4 a0 = *(const float4*)(q + s0 * D + d);
        const float4 a1 = *(const float4*)(q + s1 * D + d);
        const float4 wv = *(const float4*)(wgt + d);
        qw0[c] = make_float4(a0.x*wv.x, a0.y*wv.y, a0.z*wv.z, a0.w*wv.w);
        qw1[c] = make_float4(a1.x*wv.x, a1.y*wv.y, a1.z*wv.z, a1.w*wv.w);
    }

    // ---- Per-thread partials (28 scalars over the thread's 8 floats) ----
    // r[0..7]=dot(qw0,V[n]) r[8..15]=dot(qw1,V[n]) r[16..23]=vsq[n]
    // r[24]=ssq(P0) r[25]=ssq(P1) r[26]=dot(qw0,P0) r[27]=dot(qw1,P1)
    float r[28];
    #pragma unroll
    for (int n = 0; n < N; ++n) {
        r[n]      = dot4(qw0[0], v[n][0]) + dot4(qw0[1], v[n][1]);
        r[8 + n]  = dot4(qw1[0], v[n][0]) + dot4(qw1[1], v[n][1]);
        r[16 + n] = dot4(v[n][0], v[n][0]) + dot4(v[n][1], v[n][1]);
    }
    r[24] = dot4(p0[0], p0[0]) + dot4(p0[1], p0[1]);
    r[25] = dot4(p1[0], p1[0]) + dot4(p1[1], p1[1]);
    r[26] = dot4(qw0[0], p0[0]) + dot4(qw0[1], p0[1]);
    r[27] = dot4(qw1[0], p1[0]) + dot4(qw1[1], p1[1]);

    // ---- Wave reduce (28 independent DPP chains; totals in lane 63) ----
    #pragma unroll
    for (int i = 0; i < 28; ++i) r[i] = wave_sum63(r[i]);

    // ---- Cross-wave exchange (static indices only) ----
    if (lane == 63) {
        *(float4*)(&red[w][0])  = make_float4(r[0],  r[1],  r[2],  r[3]);
        *(float4*)(&red[w][4])  = make_float4(r[4],  r[5],  r[6],  r[7]);
        *(float4*)(&red[w][8])  = make_float4(r[8],  r[9],  r[10], r[11]);
        *(float4*)(&red[w][12]) = make_float4(r[12], r[13], r[14], r[15]);
        *(float4*)(&red[w][16]) = make_float4(r[16], r[17], r[18], r[19]);
        *(float4*)(&red[w][20]) = make_float4(r[20], r[21], r[22], r[23]);
        *(float4*)(&red[w][24]) = make_float4(r[24], r[25], r[26], r[27]);
    }
    __syncthreads();

    // ---- Combine via uniform LDS broadcasts (conflict-free, no readlanes) ----
    const int g = (w >> 1) * 2;              // first wave of this bt-group
    float rs[28];
    #pragma unroll
    for (int i = 0; i < 7; ++i) {
        const float4 A = *(const float4*)(&red[g][i*4]);
        const float4 B = *(const float4*)(&red[g + 1][i*4]);
        rs[i*4 + 0] = A.x + B.x;
        rs[i*4 + 1] = A.y + B.y;
        rs[i*4 + 2] = A.z + B.z;
        rs[i*4 + 3] = A.w + B.w;
    }

    // ---- Phase 1 softmax over n (wave-uniform scalars) ----
    float e0[N], e1[N];
    float m0 = -1e30f, m1 = -1e30f;
    #pragma unroll
    for (int n = 0; n < N; ++n) {
        const float rinv = rsqrtf(rs[16 + n] * (1.0f/1024.0f) + EPS);
        e0[n] = rs[n]     * rinv * SCALE;  m0 = fmaxf(m0, e0[n]);
        e1[n] = rs[8 + n] * rinv * SCALE;  m1 = fmaxf(m1, e1[n]);
    }
    float es0 = 0.f, es1 = 0.f;
    #pragma unroll
    for (int n = 0; n < N; ++n) {
        e0[n] = __expf(e0[n] - m0);  es0 += e0[n];
        e1[n] = __expf(e1[n] - m1);  es1 += e1[n];
    }

    // ---- Phase 2 merge scalars ----
    const float im0 = rs[26] * rsqrtf(rs[24] * (1.0f/1024.0f) + EPS) * SCALE;
    const float im1 = rs[27] * rsqrtf(rs[25] * (1.0f/1024.0f) + EPS) * SCALE;
    const float mm0 = fmaxf(m0, im0),    mm1 = fmaxf(m1, im1);
    const float wi0 = __expf(m0 - mm0),  wi1 = __expf(m1 - mm1);
    const float wa0 = __expf(im0 - mm0), wa1 = __expf(im1 - mm1);
    const float lse0 = __logf(wi0 * es0 + wa0) + mm0;   // exp(inter_lse-inter_max)==es
    const float lse1 = __logf(wi1 * es1 + wa1) + mm1;
    const float nrm0 = wi0 + wa0,         nrm1 = wi1 + wa1;
    const float cA0 = wi0 / (es0 * nrm0), cA1 = wi1 / (es1 * nrm1);
    const float cp0 = wa0 / nrm0,         cp1 = wa1 / nrm1;

    // ---- Phase E: inter_out from register-resident V; merge; nt-store ----
    #pragma unroll
    for (int c = 0; c < 2; ++c) {
        float4 A0 = make_float4(0.f,0.f,0.f,0.f);
        float4 A1 = make_float4(0.f,0.f,0.f,0.f);
        #pragma unroll
        for (int n = 0; n < N; ++n) {
            const float4 vv = v[n][c];
            A0.x += e0[n]*vv.x; A0.y += e0[n]*vv.y; A0.z += e0[n]*vv.z; A0.w += e0[n]*vv.w;
            A1.x += e1[n]*vv.x; A1.y += e1[n]*vv.y; A1.z += e1[n]*vv.z; A1.w += e1[n]*vv.w;
        }
        const float4 pc0 = p0[c], pc1 = p1[c];
        nt_store4(out + (size_t)s0 * ROW + btD + d0 + c*256,
                  cA0*A0.x + cp0*pc0.x, cA0*A0.y + cp0*pc0.y,
                  cA0*A0.z + cp0*pc0.z, cA0*A0.w + cp0*pc0.w);
        nt_store4(out + (size_t)s1 * ROW + btD + d0 + c*256,
                  cA1*A1.x + cp1*pc1.x, cA1*A1.y + cp1*pc1.y,
                  cA1*A1.z + cp1*pc1.z, cA1*A1.w + cp1*pc1.w);
    }
    if ((w & 1) == 0 && lane == 0) {         // one writer per (bt, s-pair)
        out[OUT_MM  + (size_t)s0 * BT + bt] = mm0;
        out[OUT_MM  + (size_t)s1 * BT + bt] = mm1;
        out[OUT_LSE + (size_t)s0 * BT + bt] = lse0;
        out[OUT_LSE + (size_t)s1 * BT + bt] = lse1;
    }
}

extern "C" void kernel_launch(void* const* d_in, const int* in_sizes, int n_in,
                              void* d_out, int out_size, void* d_ws, size_t ws_size,
                              hipStream_t stream) {
    const float* q   = (const float*)d_in[0];   // pseudo_queries [8,1024]
    const float* V   = (const float*)d_in[1];   // block_reps     [8,2,2048,1024]
    const float* P   = (const float*)d_in[2];   // partial_sums   [8,2,2048,1024]
    const float* wgt = (const float*)d_in[3];   // norm_weight    [1024]
    float* o = (float*)d_out;

    two_phase_attn_kernel<<<8192, TPB, 0, stream>>>(q, V, P, wgt, o);
}